// Round 1
// baseline (2949.208 us; speedup 1.0000x reference)
//
#include <hip/hip_runtime.h>

// ---------- small helpers ----------
static __device__ __forceinline__ float4 f4zero() { return make_float4(0.f, 0.f, 0.f, 0.f); }

// ---------- degree / norm kernels ----------
__global__ void k_init_deg(float* __restrict__ deg, int n) {
  int i = blockIdx.x * blockDim.x + threadIdx.x;
  if (i < n) deg[i] = 1.0f;  // self-loop
}

__global__ void k_deg(const int* __restrict__ ei, float* __restrict__ deg, int E) {
  int e = blockIdx.x * blockDim.x + threadIdx.x;
  if (e < E) unsafeAtomicAdd(&deg[ei[E + e]], 1.0f);  // dst row
}

__global__ void k_dis(float* __restrict__ d, int n) {
  int i = blockIdx.x * blockDim.x + threadIdx.x;
  if (i < n) d[i] = rsqrtf(d[i]);  // deg >= 1 always (self-loops)
}

// ---------- GEMM1: A = x @ W1 (N x 128 @ 128 x 128); B = A * dis^2 ----------
// block = 256 threads, tile = 64 rows x 128 cols, thread = 4 rows x 8 cols
// cols per thread: {4tx..4tx+3} and {64+4tx..64+4tx+3}  (2-way LDS alias = free)
__global__ __launch_bounds__(256) void k_gemm1(
    const float* __restrict__ x, const float* __restrict__ W,
    const float* __restrict__ dis, float* __restrict__ A, float* __restrict__ B, int n) {
  __shared__ float Wc[32][128];
  __shared__ float Xc[64][33];
  const int tid = threadIdx.x;
  const int tx = tid & 15;
  const int ty = tid >> 4;
  const int row0 = blockIdx.x * 64;

  float4 acc0[4], acc1[4];
#pragma unroll
  for (int r = 0; r < 4; ++r) { acc0[r] = f4zero(); acc1[r] = f4zero(); }

  for (int kc = 0; kc < 128; kc += 32) {
    // stage W chunk: 32 k-rows x 128 cols = 1024 float4
    {
      int t = tid;
#pragma unroll
      for (int it = 0; it < 4; ++it, t += 256) {
        int kk = t >> 5, cq = t & 31;
        float4 v = ((const float4*)W)[(kc + kk) * 32 + cq];
        *(float4*)&Wc[kk][cq * 4] = v;
      }
    }
    // stage X chunk: 64 rows x 32 k = 512 float4
    {
      int t = tid;
#pragma unroll
      for (int it = 0; it < 2; ++it, t += 256) {
        int r = t >> 3, kq = t & 7;
        int gi = row0 + r;
        float4 v = (gi < n) ? ((const float4*)x)[(size_t)gi * 32 + (kc >> 2) + kq] : f4zero();
        Xc[r][4 * kq + 0] = v.x; Xc[r][4 * kq + 1] = v.y;
        Xc[r][4 * kq + 2] = v.z; Xc[r][4 * kq + 3] = v.w;
      }
    }
    __syncthreads();
#pragma unroll
    for (int kk = 0; kk < 32; ++kk) {
      float4 w0 = *(const float4*)&Wc[kk][4 * tx];
      float4 w1 = *(const float4*)&Wc[kk][64 + 4 * tx];
#pragma unroll
      for (int r = 0; r < 4; ++r) {
        float a = Xc[ty * 4 + r][kk];
        acc0[r].x = fmaf(a, w0.x, acc0[r].x);
        acc0[r].y = fmaf(a, w0.y, acc0[r].y);
        acc0[r].z = fmaf(a, w0.z, acc0[r].z);
        acc0[r].w = fmaf(a, w0.w, acc0[r].w);
        acc1[r].x = fmaf(a, w1.x, acc1[r].x);
        acc1[r].y = fmaf(a, w1.y, acc1[r].y);
        acc1[r].z = fmaf(a, w1.z, acc1[r].z);
        acc1[r].w = fmaf(a, w1.w, acc1[r].w);
      }
    }
    __syncthreads();
  }
  float4* A4 = (float4*)A;
  float4* B4 = (float4*)B;
#pragma unroll
  for (int r = 0; r < 4; ++r) {
    int gi = row0 + ty * 4 + r;
    if (gi < n) {
      float ds = dis[gi];
      float idg = ds * ds;
      A4[(size_t)gi * 32 + tx] = acc0[r];
      A4[(size_t)gi * 32 + 16 + tx] = acc1[r];
      float4 s0 = acc0[r], s1 = acc1[r];
      s0.x *= idg; s0.y *= idg; s0.z *= idg; s0.w *= idg;
      s1.x *= idg; s1.y *= idg; s1.z *= idg; s1.w *= idg;
      B4[(size_t)gi * 32 + tx] = s0;
      B4[(size_t)gi * 32 + 16 + tx] = s1;
    }
  }
}

// ---------- self-loop init for layer-2 aggregation: A = relu(B + b1) * dis^2 ----------
template <bool RELU>
__global__ __launch_bounds__(256) void k_selfinit(
    const float4* __restrict__ S, float4* __restrict__ D,
    const float* __restrict__ dis, const float4* __restrict__ bias, int n) {
  int t = blockIdx.x * blockDim.x + threadIdx.x;
  if (t >= n * 32) return;
  int i = t >> 5, l = t & 31;
  float ds = dis[i];
  float idg = ds * ds;
  float4 v = S[t];
  if (RELU) {
    float4 b = bias[l];
    v.x = fmaxf(v.x + b.x, 0.f); v.y = fmaxf(v.y + b.y, 0.f);
    v.z = fmaxf(v.z + b.z, 0.f); v.w = fmaxf(v.w + b.w, 0.f);
  }
  v.x *= idg; v.y *= idg; v.z *= idg; v.w *= idg;
  D[t] = v;
}

// ---------- edge aggregation: D[dst] += dis[s]*dis[d] * f(S[src]) ----------
// 32 threads per edge, float4 per thread (128 channels)
template <bool RELU>
__global__ __launch_bounds__(256) void k_agg(
    const int* __restrict__ ei, const float* __restrict__ dis,
    const float4* __restrict__ S, float* __restrict__ D,
    const float4* __restrict__ bias, int E) {
  int t = blockIdx.x * blockDim.x + threadIdx.x;
  int e = t >> 5;
  if (e >= E) return;
  int l = t & 31;
  int s = ei[e];
  int d = ei[E + e];
  float nrm = dis[s] * dis[d];
  float4 v = S[(size_t)s * 32 + l];
  if (RELU) {
    float4 b = bias[l];
    v.x = fmaxf(v.x + b.x, 0.f); v.y = fmaxf(v.y + b.y, 0.f);
    v.z = fmaxf(v.z + b.z, 0.f); v.w = fmaxf(v.w + b.w, 0.f);
  }
  float* p = D + (size_t)d * 128 + 4 * l;
  unsafeAtomicAdd(p + 0, nrm * v.x);
  unsafeAtomicAdd(p + 1, nrm * v.y);
  unsafeAtomicAdd(p + 2, nrm * v.z);
  unsafeAtomicAdd(p + 3, nrm * v.w);
}

// ---------- GEMM2: out = g @ [Wmu | Wlv] + [bmu | blv], split-written ----------
__global__ __launch_bounds__(256) void k_gemm2(
    const float* __restrict__ g, const float* __restrict__ Wmu, const float* __restrict__ Wlv,
    const float* __restrict__ bmu, const float* __restrict__ blv,
    float* __restrict__ out, int n) {
  __shared__ float Wc[32][128];
  __shared__ float Xc[64][33];
  const int tid = threadIdx.x;
  const int tx = tid & 15;
  const int ty = tid >> 4;
  const int row0 = blockIdx.x * 64;

  float4 acc0[4], acc1[4];
#pragma unroll
  for (int r = 0; r < 4; ++r) { acc0[r] = f4zero(); acc1[r] = f4zero(); }

  for (int kc = 0; kc < 128; kc += 32) {
    {
      int t = tid;
#pragma unroll
      for (int it = 0; it < 4; ++it, t += 256) {
        int kk = t >> 5, cq = t & 31;
        float4 v = (cq < 16) ? ((const float4*)Wmu)[(kc + kk) * 16 + cq]
                             : ((const float4*)Wlv)[(kc + kk) * 16 + (cq - 16)];
        *(float4*)&Wc[kk][cq * 4] = v;
      }
    }
    {
      int t = tid;
#pragma unroll
      for (int it = 0; it < 2; ++it, t += 256) {
        int r = t >> 3, kq = t & 7;
        int gi = row0 + r;
        float4 v = (gi < n) ? ((const float4*)g)[(size_t)gi * 32 + (kc >> 2) + kq] : f4zero();
        Xc[r][4 * kq + 0] = v.x; Xc[r][4 * kq + 1] = v.y;
        Xc[r][4 * kq + 2] = v.z; Xc[r][4 * kq + 3] = v.w;
      }
    }
    __syncthreads();
#pragma unroll
    for (int kk = 0; kk < 32; ++kk) {
      float4 w0 = *(const float4*)&Wc[kk][4 * tx];       // mu cols 4tx..4tx+3
      float4 w1 = *(const float4*)&Wc[kk][64 + 4 * tx];  // lv cols 4tx..4tx+3
#pragma unroll
      for (int r = 0; r < 4; ++r) {
        float a = Xc[ty * 4 + r][kk];
        acc0[r].x = fmaf(a, w0.x, acc0[r].x);
        acc0[r].y = fmaf(a, w0.y, acc0[r].y);
        acc0[r].z = fmaf(a, w0.z, acc0[r].z);
        acc0[r].w = fmaf(a, w0.w, acc0[r].w);
        acc1[r].x = fmaf(a, w1.x, acc1[r].x);
        acc1[r].y = fmaf(a, w1.y, acc1[r].y);
        acc1[r].z = fmaf(a, w1.z, acc1[r].z);
        acc1[r].w = fmaf(a, w1.w, acc1[r].w);
      }
    }
    __syncthreads();
  }
  float4 bm = ((const float4*)bmu)[tx];
  float4 bl = ((const float4*)blv)[tx];
  float4* O4 = (float4*)out;
  const size_t lvoff = (size_t)n * 16;  // logvar start in float4 units
#pragma unroll
  for (int r = 0; r < 4; ++r) {
    int gi = row0 + ty * 4 + r;
    if (gi < n) {
      float4 m = acc0[r], v = acc1[r];
      m.x += bm.x; m.y += bm.y; m.z += bm.z; m.w += bm.w;
      v.x += bl.x; v.y += bl.y; v.z += bl.z; v.w += bl.w;
      O4[(size_t)gi * 16 + tx] = m;
      O4[lvoff + (size_t)gi * 16 + tx] = v;
    }
  }
}

extern "C" void kernel_launch(void* const* d_in, const int* in_sizes, int n_in,
                              void* d_out, int out_size, void* d_ws, size_t ws_size,
                              hipStream_t stream) {
  const float* x   = (const float*)d_in[0];
  const int*   ei  = (const int*)d_in[1];   // [2, E], row0 = src, row1 = dst
  const float* W1  = (const float*)d_in[3];
  const float* b1  = (const float*)d_in[4];
  const float* Wmu = (const float*)d_in[5];
  const float* bmu = (const float*)d_in[6];
  const float* Wlv = (const float*)d_in[7];
  const float* blv = (const float*)d_in[8];
  float* out = (float*)d_out;

  const int n = in_sizes[0] / 128;
  const int E = in_sizes[1] / 2;

  float* ws  = (float*)d_ws;
  float* dis = ws;                                   // n floats (deg -> dis in place)
  size_t aoff = (size_t)((n + 127) / 128) * 128;     // aligned
  float* A = ws + aoff;                              // n*128: xw, later g
  float* B = A + (size_t)n * 128;                    // n*128: agg1 / h-pre

  k_init_deg<<<(n + 255) / 256, 256, 0, stream>>>(dis, n);
  k_deg<<<(E + 255) / 256, 256, 0, stream>>>(ei, dis, E);
  k_dis<<<(n + 255) / 256, 256, 0, stream>>>(dis, n);

  int gblk = (n + 63) / 64;
  k_gemm1<<<gblk, 256, 0, stream>>>(x, W1, dis, A, B, n);  // A=xw, B=xw*dis^2

  int ablk = (E * 32 + 255) / 256;
  int sblk = (n * 32 + 255) / 256;
  // layer 1 aggregate: B[dst] += norm * A[src]
  k_agg<false><<<ablk, 256, 0, stream>>>(ei, dis, (const float4*)A, B, nullptr, E);
  // layer 2 self-loop init + fused relu/bias: A[i] = relu(B[i]+b1)*dis^2
  k_selfinit<true><<<sblk, 256, 0, stream>>>((const float4*)B, (float4*)A, dis,
                                             (const float4*)b1, n);
  // layer 2 aggregate: A[dst] += norm * relu(B[src]+b1)
  k_agg<true><<<ablk, 256, 0, stream>>>(ei, dis, (const float4*)B, A,
                                        (const float4*)b1, E);
  // final projections, mu -> out[0:n*64), logvar -> out[n*64:)
  k_gemm2<<<gblk, 256, 0, stream>>>(A, Wmu, Wlv, bmu, blv, out, n);
}

// Round 2
// 453.736 us; speedup vs baseline: 6.4998x; 6.4998x over previous
//
#include <hip/hip_runtime.h>

static __device__ __forceinline__ float4 f4zero() { return make_float4(0.f, 0.f, 0.f, 0.f); }

// ---------- CSR build ----------
__global__ void k_zero(int* __restrict__ cnt, int* __restrict__ gcount, int n) {
  int i = blockIdx.x * blockDim.x + threadIdx.x;
  if (i < n) cnt[i] = 0;
  if (i == 0) *gcount = 0;
}

__global__ void k_count(const int* __restrict__ ei, int* __restrict__ cnt, int E) {
  int e = blockIdx.x * blockDim.x + threadIdx.x;
  if (e < E) atomicAdd(&cnt[ei[E + e]], 1);  // dst
}

__global__ void k_prep(const int* __restrict__ cnt, float* __restrict__ dis, int n) {
  int i = blockIdx.x * blockDim.x + threadIdx.x;
  if (i < n) dis[i] = rsqrtf((float)cnt[i] + 1.0f);  // +1 self loop; deg>=1 always
}

// wave-aggregated range allocation: start[i] = running sum of cnt (order arbitrary)
__global__ void k_alloc(const int* __restrict__ cnt, int* __restrict__ start,
                        int* __restrict__ cursor, int* __restrict__ gcount, int n) {
  int i = blockIdx.x * blockDim.x + threadIdx.x;
  int lane = threadIdx.x & 63;
  int c = (i < n) ? cnt[i] : 0;
  int pre = c;  // inclusive scan over the wave
#pragma unroll
  for (int off = 1; off < 64; off <<= 1) {
    int t = __shfl_up(pre, off);
    if (lane >= off) pre += t;
  }
  int total = __shfl(pre, 63);
  int base = 0;
  if (lane == 63) base = atomicAdd(gcount, total);
  base = __shfl(base, 63);
  int st = base + pre - c;  // exclusive
  if (i < n) { start[i] = st; cursor[i] = st; }
}

__global__ void k_fill(const int* __restrict__ ei, const float* __restrict__ dis,
                       int* __restrict__ cursor, int2* __restrict__ csr, int E) {
  int e = blockIdx.x * blockDim.x + threadIdx.x;
  if (e >= E) return;
  int s = ei[e];
  int d = ei[E + e];
  int pos = atomicAdd(&cursor[d], 1);
  float nrm = dis[s] * dis[d];
  csr[pos] = make_int2(s, __float_as_int(nrm));
}

// ---------- GEMM1: A = x @ W1 (N x 128 @ 128 x 128) ----------
__global__ __launch_bounds__(256) void k_gemm1(
    const float* __restrict__ x, const float* __restrict__ W,
    float* __restrict__ A, int n) {
  __shared__ float Wc[32][128];
  __shared__ float Xc[64][33];
  const int tid = threadIdx.x;
  const int tx = tid & 15;
  const int ty = tid >> 4;
  const int row0 = blockIdx.x * 64;

  float4 acc0[4], acc1[4];
#pragma unroll
  for (int r = 0; r < 4; ++r) { acc0[r] = f4zero(); acc1[r] = f4zero(); }

  for (int kc = 0; kc < 128; kc += 32) {
    {
      int t = tid;
#pragma unroll
      for (int it = 0; it < 4; ++it, t += 256) {
        int kk = t >> 5, cq = t & 31;
        float4 v = ((const float4*)W)[(kc + kk) * 32 + cq];
        *(float4*)&Wc[kk][cq * 4] = v;
      }
    }
    {
      int t = tid;
#pragma unroll
      for (int it = 0; it < 2; ++it, t += 256) {
        int r = t >> 3, kq = t & 7;
        int gi = row0 + r;
        float4 v = (gi < n) ? ((const float4*)x)[(size_t)gi * 32 + (kc >> 2) + kq] : f4zero();
        Xc[r][4 * kq + 0] = v.x; Xc[r][4 * kq + 1] = v.y;
        Xc[r][4 * kq + 2] = v.z; Xc[r][4 * kq + 3] = v.w;
      }
    }
    __syncthreads();
#pragma unroll
    for (int kk = 0; kk < 32; ++kk) {
      float4 w0 = *(const float4*)&Wc[kk][4 * tx];
      float4 w1 = *(const float4*)&Wc[kk][64 + 4 * tx];
#pragma unroll
      for (int r = 0; r < 4; ++r) {
        float a = Xc[ty * 4 + r][kk];
        acc0[r].x = fmaf(a, w0.x, acc0[r].x);
        acc0[r].y = fmaf(a, w0.y, acc0[r].y);
        acc0[r].z = fmaf(a, w0.z, acc0[r].z);
        acc0[r].w = fmaf(a, w0.w, acc0[r].w);
        acc1[r].x = fmaf(a, w1.x, acc1[r].x);
        acc1[r].y = fmaf(a, w1.y, acc1[r].y);
        acc1[r].z = fmaf(a, w1.z, acc1[r].z);
        acc1[r].w = fmaf(a, w1.w, acc1[r].w);
      }
    }
    __syncthreads();
  }
  float4* A4 = (float4*)A;
#pragma unroll
  for (int r = 0; r < 4; ++r) {
    int gi = row0 + ty * 4 + r;
    if (gi < n) {
      A4[(size_t)gi * 32 + tx] = acc0[r];
      A4[(size_t)gi * 32 + 16 + tx] = acc1[r];
    }
  }
}

// ---------- SpMM aggregation (gather-only, no atomics) ----------
// one 64-lane wave per node; lane handles 2 channels (float2)
// D[i] = dis[i]^2 * f(S[i]) + sum_j norm_j * f(S[src_j]),  f = relu(.+b1) if RELU
template <bool RELU>
__global__ __launch_bounds__(256) void k_spmm(
    const int* __restrict__ start, const int* __restrict__ cnt,
    const int2* __restrict__ csr, const float* __restrict__ dis,
    const float2* __restrict__ S, float2* __restrict__ D,
    const float2* __restrict__ bias, int n) {
  int wid = (blockIdx.x * blockDim.x + threadIdx.x) >> 6;
  if (wid >= n) return;
  int lane = threadIdx.x & 63;
  float2 b = make_float2(0.f, 0.f);
  if (RELU) b = bias[lane];

  float ds = dis[wid];
  float idg = ds * ds;
  float2 v = S[(size_t)wid * 64 + lane];
  if (RELU) { v.x = fmaxf(v.x + b.x, 0.f); v.y = fmaxf(v.y + b.y, 0.f); }
  float2 acc = make_float2(v.x * idg, v.y * idg);

  int s0 = start[wid];
  int c = cnt[wid];
  int j = 0;
  for (; j + 1 < c; j += 2) {
    int2 e0 = csr[s0 + j];
    int2 e1 = csr[s0 + j + 1];
    float2 u0 = S[(size_t)e0.x * 64 + lane];
    float2 u1 = S[(size_t)e1.x * 64 + lane];
    float n0 = __int_as_float(e0.y);
    float n1 = __int_as_float(e1.y);
    if (RELU) {
      u0.x = fmaxf(u0.x + b.x, 0.f); u0.y = fmaxf(u0.y + b.y, 0.f);
      u1.x = fmaxf(u1.x + b.x, 0.f); u1.y = fmaxf(u1.y + b.y, 0.f);
    }
    acc.x = fmaf(n0, u0.x, acc.x); acc.y = fmaf(n0, u0.y, acc.y);
    acc.x = fmaf(n1, u1.x, acc.x); acc.y = fmaf(n1, u1.y, acc.y);
  }
  if (j < c) {
    int2 e0 = csr[s0 + j];
    float2 u0 = S[(size_t)e0.x * 64 + lane];
    float n0 = __int_as_float(e0.y);
    if (RELU) { u0.x = fmaxf(u0.x + b.x, 0.f); u0.y = fmaxf(u0.y + b.y, 0.f); }
    acc.x = fmaf(n0, u0.x, acc.x); acc.y = fmaf(n0, u0.y, acc.y);
  }
  D[(size_t)wid * 64 + lane] = acc;
}

// ---------- GEMM2: out = g @ [Wmu | Wlv] + [bmu | blv], split-written ----------
__global__ __launch_bounds__(256) void k_gemm2(
    const float* __restrict__ g, const float* __restrict__ Wmu, const float* __restrict__ Wlv,
    const float* __restrict__ bmu, const float* __restrict__ blv,
    float* __restrict__ out, int n) {
  __shared__ float Wc[32][128];
  __shared__ float Xc[64][33];
  const int tid = threadIdx.x;
  const int tx = tid & 15;
  const int ty = tid >> 4;
  const int row0 = blockIdx.x * 64;

  float4 acc0[4], acc1[4];
#pragma unroll
  for (int r = 0; r < 4; ++r) { acc0[r] = f4zero(); acc1[r] = f4zero(); }

  for (int kc = 0; kc < 128; kc += 32) {
    {
      int t = tid;
#pragma unroll
      for (int it = 0; it < 4; ++it, t += 256) {
        int kk = t >> 5, cq = t & 31;
        float4 v = (cq < 16) ? ((const float4*)Wmu)[(kc + kk) * 16 + cq]
                             : ((const float4*)Wlv)[(kc + kk) * 16 + (cq - 16)];
        *(float4*)&Wc[kk][cq * 4] = v;
      }
    }
    {
      int t = tid;
#pragma unroll
      for (int it = 0; it < 2; ++it, t += 256) {
        int r = t >> 3, kq = t & 7;
        int gi = row0 + r;
        float4 v = (gi < n) ? ((const float4*)g)[(size_t)gi * 32 + (kc >> 2) + kq] : f4zero();
        Xc[r][4 * kq + 0] = v.x; Xc[r][4 * kq + 1] = v.y;
        Xc[r][4 * kq + 2] = v.z; Xc[r][4 * kq + 3] = v.w;
      }
    }
    __syncthreads();
#pragma unroll
    for (int kk = 0; kk < 32; ++kk) {
      float4 w0 = *(const float4*)&Wc[kk][4 * tx];
      float4 w1 = *(const float4*)&Wc[kk][64 + 4 * tx];
#pragma unroll
      for (int r = 0; r < 4; ++r) {
        float a = Xc[ty * 4 + r][kk];
        acc0[r].x = fmaf(a, w0.x, acc0[r].x);
        acc0[r].y = fmaf(a, w0.y, acc0[r].y);
        acc0[r].z = fmaf(a, w0.z, acc0[r].z);
        acc0[r].w = fmaf(a, w0.w, acc0[r].w);
        acc1[r].x = fmaf(a, w1.x, acc1[r].x);
        acc1[r].y = fmaf(a, w1.y, acc1[r].y);
        acc1[r].z = fmaf(a, w1.z, acc1[r].z);
        acc1[r].w = fmaf(a, w1.w, acc1[r].w);
      }
    }
    __syncthreads();
  }
  float4 bm = ((const float4*)bmu)[tx];
  float4 bl = ((const float4*)blv)[tx];
  float4* O4 = (float4*)out;
  const size_t lvoff = (size_t)n * 16;
#pragma unroll
  for (int r = 0; r < 4; ++r) {
    int gi = row0 + ty * 4 + r;
    if (gi < n) {
      float4 m = acc0[r], v = acc1[r];
      m.x += bm.x; m.y += bm.y; m.z += bm.z; m.w += bm.w;
      v.x += bl.x; v.y += bl.y; v.z += bl.z; v.w += bl.w;
      O4[(size_t)gi * 16 + tx] = m;
      O4[lvoff + (size_t)gi * 16 + tx] = v;
    }
  }
}

extern "C" void kernel_launch(void* const* d_in, const int* in_sizes, int n_in,
                              void* d_out, int out_size, void* d_ws, size_t ws_size,
                              hipStream_t stream) {
  const float* x   = (const float*)d_in[0];
  const int*   ei  = (const int*)d_in[1];   // [2, E], row0 = src, row1 = dst
  const float* W1  = (const float*)d_in[3];
  const float* b1  = (const float*)d_in[4];
  const float* Wmu = (const float*)d_in[5];
  const float* bmu = (const float*)d_in[6];
  const float* Wlv = (const float*)d_in[7];
  const float* blv = (const float*)d_in[8];
  float* out = (float*)d_out;

  const int n = in_sizes[0] / 128;
  const int E = in_sizes[1] / 2;

  // workspace layout (float units)
  float* ws = (float*)d_ws;
  size_t p = 0;
  float* dis   = ws + p; p += n;
  int* cnt     = (int*)(ws + p); p += n;
  int* start   = (int*)(ws + p); p += n;
  int* cursor  = (int*)(ws + p); p += n;
  int* gcount  = (int*)(ws + p); p += 1;
  p = (p + 3) & ~(size_t)3;                  // 16B align
  int2* csr    = (int2*)(ws + p); p += (size_t)E * 2;
  p = (p + 3) & ~(size_t)3;
  float* A     = ws + p;                     // n*128 floats
  float* B     = out;                        // reuse d_out (n*128 floats) as layer-1 accumulator

  int nb = (n + 255) / 256;
  int eb = (E + 255) / 256;
  k_zero <<<nb, 256, 0, stream>>>(cnt, gcount, n);
  k_count<<<eb, 256, 0, stream>>>(ei, cnt, E);
  k_prep <<<nb, 256, 0, stream>>>(cnt, dis, n);
  k_alloc<<<nb, 256, 0, stream>>>(cnt, start, cursor, gcount, n);
  k_fill <<<eb, 256, 0, stream>>>(ei, dis, cursor, csr, E);

  int gblk = (n + 63) / 64;
  k_gemm1<<<gblk, 256, 0, stream>>>(x, W1, A, n);  // A = x @ W1

  int sblk = (n + 3) / 4;  // one wave per node, 4 waves/block
  // layer 1: B[i] = dis^2*A[i] + sum norm*A[src]
  k_spmm<false><<<sblk, 256, 0, stream>>>(start, cnt, csr, dis,
                                          (const float2*)A, (float2*)B, nullptr, n);
  // layer 2: A[i] = dis^2*relu(B[i]+b1) + sum norm*relu(B[src]+b1)
  k_spmm<true><<<sblk, 256, 0, stream>>>(start, cnt, csr, dis,
                                         (const float2*)B, (float2*)A,
                                         (const float2*)b1, n);
  // out = [A@Wmu+bmu | A@Wlv+blv]
  k_gemm2<<<gblk, 256, 0, stream>>>(A, Wmu, Wlv, bmu, blv, out, n);
}

// Round 3
// 394.355 us; speedup vs baseline: 7.4786x; 1.1506x over previous
//
#include <hip/hip_runtime.h>

static __device__ __forceinline__ float4 f4zero() { return make_float4(0.f, 0.f, 0.f, 0.f); }

// round-to-nearest-even f32 -> bf16 (values are finite here)
static __device__ __forceinline__ unsigned short f2bf(float f) {
  unsigned u = __float_as_uint(f);
  u += 0x7FFFu + ((u >> 16) & 1u);
  return (unsigned short)(u >> 16);
}
// packed pair of bf16 (low = first elem) -> float2
static __device__ __forceinline__ float2 bf2x2(unsigned u) {
  float2 r;
  r.x = __uint_as_float(u << 16);
  r.y = __uint_as_float(u & 0xFFFF0000u);
  return r;
}

// ---------- CSR build ----------
__global__ void k_zero(int* __restrict__ cnt, int* __restrict__ gcount, int n) {
  int i = blockIdx.x * blockDim.x + threadIdx.x;
  if (i < n) cnt[i] = 0;
  if (i == 0) *gcount = 0;
}

__global__ void k_count(const int* __restrict__ ei, int* __restrict__ cnt, int E) {
  int e = blockIdx.x * blockDim.x + threadIdx.x;
  if (e < E) atomicAdd(&cnt[ei[E + e]], 1);  // dst
}

__global__ void k_prep(const int* __restrict__ cnt, float* __restrict__ dis, int n) {
  int i = blockIdx.x * blockDim.x + threadIdx.x;
  if (i < n) dis[i] = rsqrtf((float)cnt[i] + 1.0f);  // +1 self loop
}

__global__ void k_alloc(const int* __restrict__ cnt, int* __restrict__ start,
                        int* __restrict__ cursor, int* __restrict__ gcount, int n) {
  int i = blockIdx.x * blockDim.x + threadIdx.x;
  int lane = threadIdx.x & 63;
  int c = (i < n) ? cnt[i] : 0;
  int pre = c;
#pragma unroll
  for (int off = 1; off < 64; off <<= 1) {
    int t = __shfl_up(pre, off);
    if (lane >= off) pre += t;
  }
  int total = __shfl(pre, 63);
  int base = 0;
  if (lane == 63) base = atomicAdd(gcount, total);
  base = __shfl(base, 63);
  int st = base + pre - c;
  if (i < n) { start[i] = st; cursor[i] = st; }
}

__global__ void k_fill(const int* __restrict__ ei, const float* __restrict__ dis,
                       int* __restrict__ cursor, int2* __restrict__ csr, int E) {
  int e = blockIdx.x * blockDim.x + threadIdx.x;
  if (e >= E) return;
  int s = ei[e];
  int d = ei[E + e];
  int pos = atomicAdd(&cursor[d], 1);
  float nrm = dis[s] * dis[d];
  csr[pos] = make_int2(s, __float_as_int(nrm));
}

// ---------- GEMM1: A(bf16) = x @ W1 (N x 128 @ 128 x 128) ----------
__global__ __launch_bounds__(256) void k_gemm1(
    const float* __restrict__ x, const float* __restrict__ W,
    unsigned short* __restrict__ A, int n) {
  __shared__ float Wc[32][128];
  __shared__ float Xc[64][33];
  const int tid = threadIdx.x;
  const int tx = tid & 15;
  const int ty = tid >> 4;
  const int row0 = blockIdx.x * 64;

  float4 acc0[4], acc1[4];
#pragma unroll
  for (int r = 0; r < 4; ++r) { acc0[r] = f4zero(); acc1[r] = f4zero(); }

  for (int kc = 0; kc < 128; kc += 32) {
    {
      int t = tid;
#pragma unroll
      for (int it = 0; it < 4; ++it, t += 256) {
        int kk = t >> 5, cq = t & 31;
        float4 v = ((const float4*)W)[(kc + kk) * 32 + cq];
        *(float4*)&Wc[kk][cq * 4] = v;
      }
    }
    {
      int t = tid;
#pragma unroll
      for (int it = 0; it < 2; ++it, t += 256) {
        int r = t >> 3, kq = t & 7;
        int gi = row0 + r;
        float4 v = (gi < n) ? ((const float4*)x)[(size_t)gi * 32 + (kc >> 2) + kq] : f4zero();
        Xc[r][4 * kq + 0] = v.x; Xc[r][4 * kq + 1] = v.y;
        Xc[r][4 * kq + 2] = v.z; Xc[r][4 * kq + 3] = v.w;
      }
    }
    __syncthreads();
#pragma unroll
    for (int kk = 0; kk < 32; ++kk) {
      float4 w0 = *(const float4*)&Wc[kk][4 * tx];
      float4 w1 = *(const float4*)&Wc[kk][64 + 4 * tx];
#pragma unroll
      for (int r = 0; r < 4; ++r) {
        float a = Xc[ty * 4 + r][kk];
        acc0[r].x = fmaf(a, w0.x, acc0[r].x);
        acc0[r].y = fmaf(a, w0.y, acc0[r].y);
        acc0[r].z = fmaf(a, w0.z, acc0[r].z);
        acc0[r].w = fmaf(a, w0.w, acc0[r].w);
        acc1[r].x = fmaf(a, w1.x, acc1[r].x);
        acc1[r].y = fmaf(a, w1.y, acc1[r].y);
        acc1[r].z = fmaf(a, w1.z, acc1[r].z);
        acc1[r].w = fmaf(a, w1.w, acc1[r].w);
      }
    }
    __syncthreads();
  }
  ushort4* A4 = (ushort4*)A;  // 4 bf16 = 8B per store
#pragma unroll
  for (int r = 0; r < 4; ++r) {
    int gi = row0 + ty * 4 + r;
    if (gi < n) {
      ushort4 p0, p1;
      p0.x = f2bf(acc0[r].x); p0.y = f2bf(acc0[r].y);
      p0.z = f2bf(acc0[r].z); p0.w = f2bf(acc0[r].w);
      p1.x = f2bf(acc1[r].x); p1.y = f2bf(acc1[r].y);
      p1.z = f2bf(acc1[r].z); p1.w = f2bf(acc1[r].w);
      A4[(size_t)gi * 32 + tx] = p0;
      A4[(size_t)gi * 32 + 16 + tx] = p1;
    }
  }
}

// ---------- SpMM aggregation (gather-only, bf16 table, f32 accumulate) ----------
// one 64-lane wave per node; lane handles 2 channels (one packed uint)
// acc = dis^2 * S[i] + sum_j norm_j * S[src_j]
// EPI_RELU: write relu(acc + b1) as bf16; else write acc as bf16
template <bool EPI_RELU>
__global__ __launch_bounds__(256) void k_spmm(
    const int* __restrict__ start, const int* __restrict__ cnt,
    const int2* __restrict__ csr, const float* __restrict__ dis,
    const unsigned* __restrict__ S, unsigned* __restrict__ D,
    const float2* __restrict__ bias, int n) {
  int wid = (blockIdx.x * blockDim.x + threadIdx.x) >> 6;
  if (wid >= n) return;
  int lane = threadIdx.x & 63;

  float ds = dis[wid];
  float idg = ds * ds;
  float2 v = bf2x2(S[(size_t)wid * 64 + lane]);
  float2 acc = make_float2(v.x * idg, v.y * idg);

  int s0 = start[wid];
  int c = cnt[wid];
  int j = 0;
  for (; j + 3 < c; j += 4) {
    int2 e0 = csr[s0 + j];
    int2 e1 = csr[s0 + j + 1];
    int2 e2 = csr[s0 + j + 2];
    int2 e3 = csr[s0 + j + 3];
    float2 u0 = bf2x2(S[(size_t)e0.x * 64 + lane]);
    float2 u1 = bf2x2(S[(size_t)e1.x * 64 + lane]);
    float2 u2 = bf2x2(S[(size_t)e2.x * 64 + lane]);
    float2 u3 = bf2x2(S[(size_t)e3.x * 64 + lane]);
    float n0 = __int_as_float(e0.y), n1 = __int_as_float(e1.y);
    float n2 = __int_as_float(e2.y), n3 = __int_as_float(e3.y);
    acc.x = fmaf(n0, u0.x, acc.x); acc.y = fmaf(n0, u0.y, acc.y);
    acc.x = fmaf(n1, u1.x, acc.x); acc.y = fmaf(n1, u1.y, acc.y);
    acc.x = fmaf(n2, u2.x, acc.x); acc.y = fmaf(n2, u2.y, acc.y);
    acc.x = fmaf(n3, u3.x, acc.x); acc.y = fmaf(n3, u3.y, acc.y);
  }
  for (; j < c; ++j) {
    int2 e0 = csr[s0 + j];
    float2 u0 = bf2x2(S[(size_t)e0.x * 64 + lane]);
    float n0 = __int_as_float(e0.y);
    acc.x = fmaf(n0, u0.x, acc.x); acc.y = fmaf(n0, u0.y, acc.y);
  }
  if (EPI_RELU) {
    float2 b = bias[lane];
    acc.x = fmaxf(acc.x + b.x, 0.f);
    acc.y = fmaxf(acc.y + b.y, 0.f);
  }
  unsigned pk = (unsigned)f2bf(acc.x) | ((unsigned)f2bf(acc.y) << 16);
  D[(size_t)wid * 64 + lane] = pk;
}

// ---------- GEMM2: out = g(bf16) @ [Wmu | Wlv] + [bmu | blv] ----------
__global__ __launch_bounds__(256) void k_gemm2(
    const unsigned* __restrict__ g, const float* __restrict__ Wmu,
    const float* __restrict__ Wlv, const float* __restrict__ bmu,
    const float* __restrict__ blv, float* __restrict__ out, int n) {
  __shared__ float Wc[32][128];
  __shared__ float Xc[64][33];
  const int tid = threadIdx.x;
  const int tx = tid & 15;
  const int ty = tid >> 4;
  const int row0 = blockIdx.x * 64;

  float4 acc0[4], acc1[4];
#pragma unroll
  for (int r = 0; r < 4; ++r) { acc0[r] = f4zero(); acc1[r] = f4zero(); }

  for (int kc = 0; kc < 128; kc += 32) {
    {
      int t = tid;
#pragma unroll
      for (int it = 0; it < 4; ++it, t += 256) {
        int kk = t >> 5, cq = t & 31;
        float4 v = (cq < 16) ? ((const float4*)Wmu)[(kc + kk) * 16 + cq]
                             : ((const float4*)Wlv)[(kc + kk) * 16 + (cq - 16)];
        *(float4*)&Wc[kk][cq * 4] = v;
      }
    }
    {
      // stage 64 rows x 32 k of bf16 g: one uint4 (8 bf16) per thread
      int r = tid >> 2, q = tid & 3;
      int gi = row0 + r;
      uint4 u = (gi < n) ? ((const uint4*)g)[(size_t)gi * 16 + (kc >> 3) + q]
                         : make_uint4(0, 0, 0, 0);
      float2 f0 = bf2x2(u.x), f1 = bf2x2(u.y), f2 = bf2x2(u.z), f3 = bf2x2(u.w);
      float* xr = &Xc[r][8 * q];
      xr[0] = f0.x; xr[1] = f0.y; xr[2] = f1.x; xr[3] = f1.y;
      xr[4] = f2.x; xr[5] = f2.y; xr[6] = f3.x; xr[7] = f3.y;
    }
    __syncthreads();
#pragma unroll
    for (int kk = 0; kk < 32; ++kk) {
      float4 w0 = *(const float4*)&Wc[kk][4 * tx];
      float4 w1 = *(const float4*)&Wc[kk][64 + 4 * tx];
#pragma unroll
      for (int r = 0; r < 4; ++r) {
        float a = Xc[ty * 4 + r][kk];
        acc0[r].x = fmaf(a, w0.x, acc0[r].x);
        acc0[r].y = fmaf(a, w0.y, acc0[r].y);
        acc0[r].z = fmaf(a, w0.z, acc0[r].z);
        acc0[r].w = fmaf(a, w0.w, acc0[r].w);
        acc1[r].x = fmaf(a, w1.x, acc1[r].x);
        acc1[r].y = fmaf(a, w1.y, acc1[r].y);
        acc1[r].z = fmaf(a, w1.z, acc1[r].z);
        acc1[r].w = fmaf(a, w1.w, acc1[r].w);
      }
    }
    __syncthreads();
  }
  float4 bm = ((const float4*)bmu)[tx];
  float4 bl = ((const float4*)blv)[tx];
  float4* O4 = (float4*)out;
  const size_t lvoff = (size_t)n * 16;
#pragma unroll
  for (int r = 0; r < 4; ++r) {
    int gi = row0 + ty * 4 + r;
    if (gi < n) {
      float4 m = acc0[r], v = acc1[r];
      m.x += bm.x; m.y += bm.y; m.z += bm.z; m.w += bm.w;
      v.x += bl.x; v.y += bl.y; v.z += bl.z; v.w += bl.w;
      O4[(size_t)gi * 16 + tx] = m;
      O4[lvoff + (size_t)gi * 16 + tx] = v;
    }
  }
}

extern "C" void kernel_launch(void* const* d_in, const int* in_sizes, int n_in,
                              void* d_out, int out_size, void* d_ws, size_t ws_size,
                              hipStream_t stream) {
  const float* x   = (const float*)d_in[0];
  const int*   ei  = (const int*)d_in[1];   // [2, E], row0 = src, row1 = dst
  const float* W1  = (const float*)d_in[3];
  const float* b1  = (const float*)d_in[4];
  const float* Wmu = (const float*)d_in[5];
  const float* bmu = (const float*)d_in[6];
  const float* Wlv = (const float*)d_in[7];
  const float* blv = (const float*)d_in[8];
  float* out = (float*)d_out;

  const int n = in_sizes[0] / 128;
  const int E = in_sizes[1] / 2;

  // workspace layout (float units)
  float* ws = (float*)d_ws;
  size_t p = 0;
  float* dis  = ws + p; p += n;
  int* cnt    = (int*)(ws + p); p += n;
  int* start  = (int*)(ws + p); p += n;
  int* cursor = (int*)(ws + p); p += n;
  int* gcount = (int*)(ws + p); p += 1;
  p = (p + 3) & ~(size_t)3;  // 16B align
  int2* csr   = (int2*)(ws + p); p += (size_t)E * 2;
  p = (p + 3) & ~(size_t)3;
  unsigned* A = (unsigned*)(ws + p); p += (size_t)n * 64;  // n*128 bf16 = n*64 uint
  unsigned* H = (unsigned*)(ws + p); p += (size_t)n * 64;
  unsigned* G = (unsigned*)(ws + p); p += (size_t)n * 64;

  int nb = (n + 255) / 256;
  int eb = (E + 255) / 256;
  k_zero <<<nb, 256, 0, stream>>>(cnt, gcount, n);
  k_count<<<eb, 256, 0, stream>>>(ei, cnt, E);
  k_prep <<<nb, 256, 0, stream>>>(cnt, dis, n);
  k_alloc<<<nb, 256, 0, stream>>>(cnt, start, cursor, gcount, n);
  k_fill <<<eb, 256, 0, stream>>>(ei, dis, cursor, csr, E);

  int gblk = (n + 63) / 64;
  k_gemm1<<<gblk, 256, 0, stream>>>(x, W1, (unsigned short*)A, n);  // A = bf16(x @ W1)

  int sblk = (n + 3) / 4;  // one wave per node, 4 waves/block
  // layer 1: H = bf16(relu(dis^2*A[i] + sum norm*A[src] + b1))
  k_spmm<true><<<sblk, 256, 0, stream>>>(start, cnt, csr, dis, A, H,
                                         (const float2*)b1, n);
  // layer 2: G = bf16(dis^2*H[i] + sum norm*H[src])
  k_spmm<false><<<sblk, 256, 0, stream>>>(start, cnt, csr, dis, H, G, nullptr, n);
  // out = [G@Wmu+bmu | G@Wlv+blv]
  k_gemm2<<<gblk, 256, 0, stream>>>(G, Wmu, Wlv, bmu, blv, out, n);
}

// Round 4
// 349.834 us; speedup vs baseline: 8.4303x; 1.1273x over previous
//
#include <hip/hip_runtime.h>

typedef short bf16x8 __attribute__((ext_vector_type(8)));
typedef float f32x4 __attribute__((ext_vector_type(4)));

static __device__ __forceinline__ float4 f4zero() { return make_float4(0.f, 0.f, 0.f, 0.f); }

// round-to-nearest-even f32 -> bf16
static __device__ __forceinline__ unsigned short f2bf(float f) {
  unsigned u = __float_as_uint(f);
  u += 0x7FFFu + ((u >> 16) & 1u);
  return (unsigned short)(u >> 16);
}
// packed pair of bf16 (low = first elem) -> float2
static __device__ __forceinline__ float2 bf2x2(unsigned u) {
  float2 r;
  r.x = __uint_as_float(u << 16);
  r.y = __uint_as_float(u & 0xFFFF0000u);
  return r;
}

// ---------- CSR build ----------
__global__ void k_zero(int* __restrict__ cnt, int* __restrict__ gcount, int n) {
  int i = blockIdx.x * blockDim.x + threadIdx.x;
  if (i < n) cnt[i] = 0;
  if (i == 0) *gcount = 0;
}

__global__ void k_count(const int* __restrict__ ei, int* __restrict__ cnt, int E) {
  int e = blockIdx.x * blockDim.x + threadIdx.x;
  if (e < E) atomicAdd(&cnt[ei[E + e]], 1);  // dst
}

__global__ void k_prep(const int* __restrict__ cnt, float* __restrict__ dis, int n) {
  int i = blockIdx.x * blockDim.x + threadIdx.x;
  if (i < n) dis[i] = rsqrtf((float)cnt[i] + 1.0f);  // +1 self loop
}

__global__ void k_alloc(const int* __restrict__ cnt, int* __restrict__ start,
                        int* __restrict__ cursor, int* __restrict__ gcount, int n) {
  int i = blockIdx.x * blockDim.x + threadIdx.x;
  int lane = threadIdx.x & 63;
  int c = (i < n) ? cnt[i] : 0;
  int pre = c;
#pragma unroll
  for (int off = 1; off < 64; off <<= 1) {
    int t = __shfl_up(pre, off);
    if (lane >= off) pre += t;
  }
  int total = __shfl(pre, 63);
  int base = 0;
  if (lane == 63) base = atomicAdd(gcount, total);
  base = __shfl(base, 63);
  int st = base + pre - c;
  if (i < n) { start[i] = st; cursor[i] = st; }
}

__global__ void k_fill(const int* __restrict__ ei, const float* __restrict__ dis,
                       int* __restrict__ cursor, int2* __restrict__ csr, int E) {
  int e = blockIdx.x * blockDim.x + threadIdx.x;
  if (e >= E) return;
  int s = ei[e];
  int d = ei[E + e];
  int pos = atomicAdd(&cursor[d], 1);
  float nrm = dis[s] * dis[d];
  csr[pos] = make_int2(s, __float_as_int(nrm));
}

// ---------- weight transpose/pack: Wt1[n][k]=W1[k][n]; Wt2[n][k]=[Wmu|Wlv][k][n] ----------
__global__ void k_twt(const float* __restrict__ W1, const float* __restrict__ Wmu,
                      const float* __restrict__ Wlv,
                      unsigned short* __restrict__ Wt1, unsigned short* __restrict__ Wt2) {
  int id = blockIdx.x * 256 + threadIdx.x;  // 0..32767
  if (id < 16384) {
    int nn = id >> 7, k = id & 127;
    Wt1[id] = f2bf(W1[k * 128 + nn]);
  } else {
    int id2 = id - 16384;
    int nn = id2 >> 7, k = id2 & 127;
    float v = (nn < 64) ? Wmu[k * 64 + nn] : Wlv[k * 64 + (nn - 64)];
    Wt2[id2] = f2bf(v);
  }
}

// ---------- GEMM1 (MFMA): A(bf16) = x(f32) @ W1, via Wt1[n][k] ----------
// block 256 = 4 waves; block tile 64 rows x 128 cols; wave = 16 rows x 128 cols
__global__ __launch_bounds__(256) void k_gemm1_mfma(
    const float* __restrict__ x, const unsigned short* __restrict__ Wt,
    unsigned short* __restrict__ A, int n) {
  __shared__ unsigned short Wl[128 * 136];  // padded rows: +8 bf16
  __shared__ unsigned short Xl[64 * 136];
  const int tid = threadIdx.x;
  const int row0 = blockIdx.x * 64;
  // stage Wt (bf16, coalesced uint4)
  {
    const uint4* Wg = (const uint4*)Wt;
#pragma unroll
    for (int i = 0; i < 8; ++i) {
      int idx = tid + i * 256;  // 0..2047
      int r = idx >> 4, c = idx & 15;
      *(uint4*)&Wl[r * 136 + c * 8] = Wg[r * 16 + c];
    }
  }
  // stage x tile, f32 -> bf16
  {
#pragma unroll
    for (int i = 0; i < 8; ++i) {
      int idx = tid + i * 256;  // 0..2047
      int r = idx >> 5, c = idx & 31;
      int gi = row0 + r;
      float4 v = (gi < n) ? ((const float4*)x)[(size_t)gi * 32 + c] : f4zero();
      ushort4 p;
      p.x = f2bf(v.x); p.y = f2bf(v.y); p.z = f2bf(v.z); p.w = f2bf(v.w);
      *(ushort4*)&Xl[r * 136 + c * 4] = p;
    }
  }
  __syncthreads();

  const int wave = tid >> 6, lane = tid & 63;
  const int li = lane & 15, quad = lane >> 4;
  const int m0 = wave * 16;
  f32x4 acc[8];
#pragma unroll
  for (int t = 0; t < 8; ++t) acc[t] = (f32x4){0.f, 0.f, 0.f, 0.f};

#pragma unroll
  for (int kk = 0; kk < 4; ++kk) {
    int ko = kk * 32 + quad * 8;
    bf16x8 a = *(const bf16x8*)&Xl[(m0 + li) * 136 + ko];
#pragma unroll
    for (int nt = 0; nt < 8; ++nt) {
      bf16x8 b = *(const bf16x8*)&Wl[(nt * 16 + li) * 136 + ko];
      acc[nt] = __builtin_amdgcn_mfma_f32_16x16x32_bf16(a, b, acc[nt], 0, 0, 0);
    }
  }
#pragma unroll
  for (int nt = 0; nt < 8; ++nt) {
#pragma unroll
    for (int r = 0; r < 4; ++r) {
      int gi = row0 + m0 + quad * 4 + r;
      if (gi < n) A[(size_t)gi * 128 + nt * 16 + li] = f2bf(acc[nt][r]);
    }
  }
}

// ---------- GEMM2 (MFMA): out = [G@Wmu+bmu | G@Wlv+blv] via Wt2[n][k] ----------
__global__ __launch_bounds__(256) void k_gemm2_mfma(
    const unsigned short* __restrict__ G, const unsigned short* __restrict__ Wt,
    const float* __restrict__ bmu, const float* __restrict__ blv,
    float* __restrict__ out, int n) {
  __shared__ unsigned short Wl[128 * 136];
  __shared__ unsigned short Xl[64 * 136];
  const int tid = threadIdx.x;
  const int row0 = blockIdx.x * 64;
  {
    const uint4* Wg = (const uint4*)Wt;
#pragma unroll
    for (int i = 0; i < 8; ++i) {
      int idx = tid + i * 256;
      int r = idx >> 4, c = idx & 15;
      *(uint4*)&Wl[r * 136 + c * 8] = Wg[r * 16 + c];
    }
  }
  {
    const uint4* Gg = (const uint4*)G;
#pragma unroll
    for (int i = 0; i < 4; ++i) {
      int idx = tid + i * 256;  // 0..1023
      int r = idx >> 4, c = idx & 15;
      int gi = row0 + r;
      uint4 v = (gi < n) ? Gg[(size_t)gi * 16 + c] : make_uint4(0, 0, 0, 0);
      *(uint4*)&Xl[r * 136 + c * 8] = v;
    }
  }
  __syncthreads();

  const int wave = tid >> 6, lane = tid & 63;
  const int li = lane & 15, quad = lane >> 4;
  const int m0 = wave * 16;

  float bias[8];
#pragma unroll
  for (int nt = 0; nt < 8; ++nt) {
    int c = nt * 16 + li;
    bias[nt] = (c < 64) ? bmu[c] : blv[c - 64];
  }

  f32x4 acc[8];
#pragma unroll
  for (int t = 0; t < 8; ++t) acc[t] = (f32x4){0.f, 0.f, 0.f, 0.f};

#pragma unroll
  for (int kk = 0; kk < 4; ++kk) {
    int ko = kk * 32 + quad * 8;
    bf16x8 a = *(const bf16x8*)&Xl[(m0 + li) * 136 + ko];
#pragma unroll
    for (int nt = 0; nt < 8; ++nt) {
      bf16x8 b = *(const bf16x8*)&Wl[(nt * 16 + li) * 136 + ko];
      acc[nt] = __builtin_amdgcn_mfma_f32_16x16x32_bf16(a, b, acc[nt], 0, 0, 0);
    }
  }
#pragma unroll
  for (int nt = 0; nt < 8; ++nt) {
    int col = nt * 16 + li;
#pragma unroll
    for (int r = 0; r < 4; ++r) {
      int gi = row0 + m0 + quad * 4 + r;
      if (gi < n) {
        float v = acc[nt][r] + bias[nt];
        if (col < 64) out[(size_t)gi * 64 + col] = v;                       // mu
        else          out[(size_t)(n + gi) * 64 + (col - 64)] = v;          // logvar
      }
    }
  }
}

// ---------- SpMM aggregation (gather-only, bf16 table, f32 accumulate) ----------
template <bool EPI_RELU>
__global__ __launch_bounds__(256) void k_spmm(
    const int* __restrict__ start, const int* __restrict__ cnt,
    const int2* __restrict__ csr, const float* __restrict__ dis,
    const unsigned* __restrict__ S, unsigned* __restrict__ D,
    const float2* __restrict__ bias, int n) {
  int wid = (blockIdx.x * blockDim.x + threadIdx.x) >> 6;
  if (wid >= n) return;
  int lane = threadIdx.x & 63;

  float ds = dis[wid];
  float idg = ds * ds;
  float2 v = bf2x2(S[(size_t)wid * 64 + lane]);
  float2 acc = make_float2(v.x * idg, v.y * idg);

  int s0 = start[wid];
  int c = cnt[wid];
  int j = 0;
  for (; j + 3 < c; j += 4) {
    int2 e0 = csr[s0 + j];
    int2 e1 = csr[s0 + j + 1];
    int2 e2 = csr[s0 + j + 2];
    int2 e3 = csr[s0 + j + 3];
    float2 u0 = bf2x2(S[(size_t)e0.x * 64 + lane]);
    float2 u1 = bf2x2(S[(size_t)e1.x * 64 + lane]);
    float2 u2 = bf2x2(S[(size_t)e2.x * 64 + lane]);
    float2 u3 = bf2x2(S[(size_t)e3.x * 64 + lane]);
    float n0 = __int_as_float(e0.y), n1 = __int_as_float(e1.y);
    float n2 = __int_as_float(e2.y), n3 = __int_as_float(e3.y);
    acc.x = fmaf(n0, u0.x, acc.x); acc.y = fmaf(n0, u0.y, acc.y);
    acc.x = fmaf(n1, u1.x, acc.x); acc.y = fmaf(n1, u1.y, acc.y);
    acc.x = fmaf(n2, u2.x, acc.x); acc.y = fmaf(n2, u2.y, acc.y);
    acc.x = fmaf(n3, u3.x, acc.x); acc.y = fmaf(n3, u3.y, acc.y);
  }
  for (; j < c; ++j) {
    int2 e0 = csr[s0 + j];
    float2 u0 = bf2x2(S[(size_t)e0.x * 64 + lane]);
    float n0 = __int_as_float(e0.y);
    acc.x = fmaf(n0, u0.x, acc.x); acc.y = fmaf(n0, u0.y, acc.y);
  }
  if (EPI_RELU) {
    float2 b = bias[lane];
    acc.x = fmaxf(acc.x + b.x, 0.f);
    acc.y = fmaxf(acc.y + b.y, 0.f);
  }
  unsigned pk = (unsigned)f2bf(acc.x) | ((unsigned)f2bf(acc.y) << 16);
  D[(size_t)wid * 64 + lane] = pk;
}

extern "C" void kernel_launch(void* const* d_in, const int* in_sizes, int n_in,
                              void* d_out, int out_size, void* d_ws, size_t ws_size,
                              hipStream_t stream) {
  const float* x   = (const float*)d_in[0];
  const int*   ei  = (const int*)d_in[1];   // [2, E], row0 = src, row1 = dst
  const float* W1  = (const float*)d_in[3];
  const float* b1  = (const float*)d_in[4];
  const float* Wmu = (const float*)d_in[5];
  const float* bmu = (const float*)d_in[6];
  const float* Wlv = (const float*)d_in[7];
  const float* blv = (const float*)d_in[8];
  float* out = (float*)d_out;

  const int n = in_sizes[0] / 128;
  const int E = in_sizes[1] / 2;

  // workspace layout (float units)
  float* ws = (float*)d_ws;
  size_t p = 0;
  float* dis  = ws + p; p += n;
  int* cnt    = (int*)(ws + p); p += n;
  int* start  = (int*)(ws + p); p += n;
  int* cursor = (int*)(ws + p); p += n;
  int* gcount = (int*)(ws + p); p += 1;
  p = (p + 3) & ~(size_t)3;  // 16B align
  int2* csr   = (int2*)(ws + p); p += (size_t)E * 2;
  p = (p + 3) & ~(size_t)3;
  unsigned* A = (unsigned*)(ws + p); p += (size_t)n * 64;  // n*128 bf16
  unsigned* H = (unsigned*)(ws + p); p += (size_t)n * 64;
  unsigned* G = (unsigned*)(ws + p); p += (size_t)n * 64;
  unsigned short* Wt1 = (unsigned short*)(ws + p); p += 8192;  // 128x128 bf16
  unsigned short* Wt2 = (unsigned short*)(ws + p); p += 8192;

  int nb = (n + 255) / 256;
  int eb = (E + 255) / 256;
  k_twt  <<<128, 256, 0, stream>>>(W1, Wmu, Wlv, Wt1, Wt2);
  k_zero <<<nb, 256, 0, stream>>>(cnt, gcount, n);
  k_count<<<eb, 256, 0, stream>>>(ei, cnt, E);
  k_prep <<<nb, 256, 0, stream>>>(cnt, dis, n);
  k_alloc<<<nb, 256, 0, stream>>>(cnt, start, cursor, gcount, n);
  k_fill <<<eb, 256, 0, stream>>>(ei, dis, cursor, csr, E);

  int gblk = (n + 63) / 64;
  k_gemm1_mfma<<<gblk, 256, 0, stream>>>(x, Wt1, (unsigned short*)A, n);

  int sblk = (n + 3) / 4;  // one wave per node
  // layer 1: H = bf16(relu(dis^2*A[i] + sum norm*A[src] + b1))
  k_spmm<true><<<sblk, 256, 0, stream>>>(start, cnt, csr, dis, A, H,
                                         (const float2*)b1, n);
  // layer 2: G = bf16(dis^2*H[i] + sum norm*H[src])
  k_spmm<false><<<sblk, 256, 0, stream>>>(start, cnt, csr, dis, H, G, nullptr, n);
  // out = [G@Wmu+bmu | G@Wlv+blv]
  k_gemm2_mfma<<<gblk, 256, 0, stream>>>((const unsigned short*)G, Wt2, bmu, blv, out, n);
}

// Round 5
// 297.371 us; speedup vs baseline: 9.9176x; 1.1764x over previous
//
#include <hip/hip_runtime.h>

typedef short bf16x8 __attribute__((ext_vector_type(8)));
typedef float f32x4 __attribute__((ext_vector_type(4)));

#define ELLK 32
#define OCAP 4096

static __device__ __forceinline__ float4 f4zero() { return make_float4(0.f, 0.f, 0.f, 0.f); }

// round-to-nearest-even f32 -> bf16
static __device__ __forceinline__ unsigned short f2bf(float f) {
  unsigned u = __float_as_uint(f);
  u += 0x7FFFu + ((u >> 16) & 1u);
  return (unsigned short)(u >> 16);
}
// packed pair of bf16 (low = first elem) -> float2
static __device__ __forceinline__ float2 bf2x2(unsigned u) {
  float2 r;
  r.x = __uint_as_float(u << 16);
  r.y = __uint_as_float(u & 0xFFFF0000u);
  return r;
}

// ---------- setup: zero cnt/ocount + transpose weights to bf16 Wt[n][k] ----------
__global__ void k_setup(const float* __restrict__ W1, const float* __restrict__ Wmu,
                        const float* __restrict__ Wlv, unsigned short* __restrict__ Wt1,
                        unsigned short* __restrict__ Wt2, int* __restrict__ cnt,
                        int* __restrict__ ocount, int n, int nbz) {
  int b = blockIdx.x;
  if (b < nbz) {
    int i = b * 256 + threadIdx.x;
    if (i < n) cnt[i] = 0;
    if (b == 0 && threadIdx.x == 0) *ocount = 0;
  } else {
    int id = (b - nbz) * 256 + threadIdx.x;  // 0..32767
    if (id < 16384) {
      int nn = id >> 7, k = id & 127;
      Wt1[id] = f2bf(W1[k * 128 + nn]);
    } else {
      int id2 = id - 16384;
      int nn = id2 >> 7, k = id2 & 127;
      float v = (nn < 64) ? Wmu[k * 64 + nn] : Wlv[k * 64 + (nn - 64)];
      Wt2[id2] = f2bf(v);
    }
  }
}

// ---------- fused: GEMM1 (MFMA, first gblk blocks) + ELL fill (remaining blocks) ----------
// gemm1: A(bf16) = x(f32) @ W1 via Wt1[n][k]; block tile 64 rows x 128 cols, 4 waves
// fill:  pos = atomicAdd(cnt[dst]); ell[dst*ELLK+pos] = src  (overflow -> ovf list)
__global__ __launch_bounds__(256) void k_gemm1_fill(
    const float* __restrict__ x, const unsigned short* __restrict__ Wt,
    unsigned short* __restrict__ A, const int* __restrict__ ei,
    int* __restrict__ cnt, int* __restrict__ ell, int2* __restrict__ ovf,
    int* __restrict__ ocount, int n, int E, int gblk) {
  __shared__ unsigned short Wl[128 * 136];  // padded rows: +8 bf16
  __shared__ unsigned short Xl[64 * 136];
  if (blockIdx.x >= gblk) {
    int e = (blockIdx.x - gblk) * 256 + threadIdx.x;
    if (e < E) {
      int s = ei[e];
      int d = ei[E + e];
      int pos = atomicAdd(&cnt[d], 1);
      if (pos < ELLK) {
        ell[d * ELLK + pos] = s;
      } else {
        int o = atomicAdd(ocount, 1);
        if (o < OCAP) ovf[o] = make_int2(d, s);
      }
    }
    return;
  }
  const int tid = threadIdx.x;
  const int row0 = blockIdx.x * 64;
  // stage Wt (bf16, coalesced uint4)
  {
    const uint4* Wg = (const uint4*)Wt;
#pragma unroll
    for (int i = 0; i < 8; ++i) {
      int idx = tid + i * 256;  // 0..2047
      int r = idx >> 4, c = idx & 15;
      *(uint4*)&Wl[r * 136 + c * 8] = Wg[r * 16 + c];
    }
  }
  // stage x tile, f32 -> bf16
  {
#pragma unroll
    for (int i = 0; i < 8; ++i) {
      int idx = tid + i * 256;  // 0..2047
      int r = idx >> 5, c = idx & 31;
      int gi = row0 + r;
      float4 v = (gi < n) ? ((const float4*)x)[(size_t)gi * 32 + c] : f4zero();
      ushort4 p;
      p.x = f2bf(v.x); p.y = f2bf(v.y); p.z = f2bf(v.z); p.w = f2bf(v.w);
      *(ushort4*)&Xl[r * 136 + c * 4] = p;
    }
  }
  __syncthreads();

  const int wave = tid >> 6, lane = tid & 63;
  const int li = lane & 15, quad = lane >> 4;
  const int m0 = wave * 16;
  f32x4 acc[8];
#pragma unroll
  for (int t = 0; t < 8; ++t) acc[t] = (f32x4){0.f, 0.f, 0.f, 0.f};

#pragma unroll
  for (int kk = 0; kk < 4; ++kk) {
    int ko = kk * 32 + quad * 8;
    bf16x8 a = *(const bf16x8*)&Xl[(m0 + li) * 136 + ko];
#pragma unroll
    for (int nt = 0; nt < 8; ++nt) {
      bf16x8 b = *(const bf16x8*)&Wl[(nt * 16 + li) * 136 + ko];
      acc[nt] = __builtin_amdgcn_mfma_f32_16x16x32_bf16(a, b, acc[nt], 0, 0, 0);
    }
  }
  // repack through LDS for coalesced 16B stores
  __syncthreads();
#pragma unroll
  for (int nt = 0; nt < 8; ++nt)
#pragma unroll
    for (int r = 0; r < 4; ++r)
      Xl[(m0 + quad * 4 + r) * 136 + nt * 16 + li] = f2bf(acc[nt][r]);
  __syncthreads();
  {
    uint4* A4 = (uint4*)A;
#pragma unroll
    for (int i = 0; i < 4; ++i) {
      int idx = tid + i * 256;  // 0..1023
      int r = idx >> 4, c = idx & 15;
      int gi = row0 + r;
      if (gi < n) A4[(size_t)gi * 16 + c] = *(uint4*)&Xl[r * 136 + c * 8];
    }
  }
}

// ---------- SpMM aggregation over ELL (gather-only, bf16 table, f32 accumulate) ----------
// one 64-lane wave per node; lane = 2 channels (packed uint)
// acc = S[i]/(deg_i) + sum_j S[src_j] * rsqrt(deg_i)*rsqrt(deg_src)
template <bool EPI_RELU>
__global__ __launch_bounds__(256) void k_spmm(
    const int* __restrict__ cnt, const int* __restrict__ ell,
    const int2* __restrict__ ovf, const int* __restrict__ ocount,
    const unsigned* __restrict__ S, unsigned* __restrict__ D,
    const float2* __restrict__ bias, int n) {
  int wid = (blockIdx.x * blockDim.x + threadIdx.x) >> 6;
  if (wid >= n) return;
  int lane = threadIdx.x & 63;

  int c = cnt[wid];
  float fc = (float)(c + 1);
  float dsd = rsqrtf(fc);
  float idg = dsd * dsd;
  float2 v = bf2x2(S[(size_t)wid * 64 + lane]);
  float2 acc = make_float2(v.x * idg, v.y * idg);

  const int* row = ell + (size_t)wid * ELLK;
  int m = (c < ELLK) ? c : ELLK;
  int j = 0;
  for (; j + 3 < m; j += 4) {
    int4 ss = *(const int4*)(row + j);
    float n0 = dsd * rsqrtf((float)(cnt[ss.x] + 1));
    float n1 = dsd * rsqrtf((float)(cnt[ss.y] + 1));
    float n2 = dsd * rsqrtf((float)(cnt[ss.z] + 1));
    float n3 = dsd * rsqrtf((float)(cnt[ss.w] + 1));
    float2 u0 = bf2x2(S[(size_t)ss.x * 64 + lane]);
    float2 u1 = bf2x2(S[(size_t)ss.y * 64 + lane]);
    float2 u2 = bf2x2(S[(size_t)ss.z * 64 + lane]);
    float2 u3 = bf2x2(S[(size_t)ss.w * 64 + lane]);
    acc.x = fmaf(n0, u0.x, acc.x); acc.y = fmaf(n0, u0.y, acc.y);
    acc.x = fmaf(n1, u1.x, acc.x); acc.y = fmaf(n1, u1.y, acc.y);
    acc.x = fmaf(n2, u2.x, acc.x); acc.y = fmaf(n2, u2.y, acc.y);
    acc.x = fmaf(n3, u3.x, acc.x); acc.y = fmaf(n3, u3.y, acc.y);
  }
  for (; j < m; ++j) {
    int s = row[j];
    float n0 = dsd * rsqrtf((float)(cnt[s] + 1));
    float2 u0 = bf2x2(S[(size_t)s * 64 + lane]);
    acc.x = fmaf(n0, u0.x, acc.x); acc.y = fmaf(n0, u0.y, acc.y);
  }
  if (c > ELLK) {  // pathological high-degree nodes: scan tiny overflow list
    int oc = *ocount;
    if (oc > OCAP) oc = OCAP;
    for (int k = 0; k < oc; ++k) {
      int2 e = ovf[k];
      if (e.x == wid) {
        float n0 = dsd * rsqrtf((float)(cnt[e.y] + 1));
        float2 u0 = bf2x2(S[(size_t)e.y * 64 + lane]);
        acc.x = fmaf(n0, u0.x, acc.x); acc.y = fmaf(n0, u0.y, acc.y);
      }
    }
  }
  if (EPI_RELU) {
    float2 b = bias[lane];
    acc.x = fmaxf(acc.x + b.x, 0.f);
    acc.y = fmaxf(acc.y + b.y, 0.f);
  }
  unsigned pk = (unsigned)f2bf(acc.x) | ((unsigned)f2bf(acc.y) << 16);
  D[(size_t)wid * 64 + lane] = pk;
}

// ---------- GEMM2 (MFMA): out = [G@Wmu+bmu | G@Wlv+blv] via Wt2[n][k] ----------
__global__ __launch_bounds__(256) void k_gemm2_mfma(
    const unsigned short* __restrict__ G, const unsigned short* __restrict__ Wt,
    const float* __restrict__ bmu, const float* __restrict__ blv,
    float* __restrict__ out, int n) {
  __shared__ unsigned short Wl[128 * 136];
  __shared__ unsigned short Xl[64 * 136];
  const int tid = threadIdx.x;
  const int row0 = blockIdx.x * 64;
  {
    const uint4* Wg = (const uint4*)Wt;
#pragma unroll
    for (int i = 0; i < 8; ++i) {
      int idx = tid + i * 256;
      int r = idx >> 4, c = idx & 15;
      *(uint4*)&Wl[r * 136 + c * 8] = Wg[r * 16 + c];
    }
  }
  {
    const uint4* Gg = (const uint4*)G;
#pragma unroll
    for (int i = 0; i < 4; ++i) {
      int idx = tid + i * 256;  // 0..1023
      int r = idx >> 4, c = idx & 15;
      int gi = row0 + r;
      uint4 v = (gi < n) ? Gg[(size_t)gi * 16 + c] : make_uint4(0, 0, 0, 0);
      *(uint4*)&Xl[r * 136 + c * 8] = v;
    }
  }
  __syncthreads();

  const int wave = tid >> 6, lane = tid & 63;
  const int li = lane & 15, quad = lane >> 4;
  const int m0 = wave * 16;

  float bias[8];
#pragma unroll
  for (int nt = 0; nt < 8; ++nt) {
    int c = nt * 16 + li;
    bias[nt] = (c < 64) ? bmu[c] : blv[c - 64];
  }

  f32x4 acc[8];
#pragma unroll
  for (int t = 0; t < 8; ++t) acc[t] = (f32x4){0.f, 0.f, 0.f, 0.f};

#pragma unroll
  for (int kk = 0; kk < 4; ++kk) {
    int ko = kk * 32 + quad * 8;
    bf16x8 a = *(const bf16x8*)&Xl[(m0 + li) * 136 + ko];
#pragma unroll
    for (int nt = 0; nt < 8; ++nt) {
      bf16x8 b = *(const bf16x8*)&Wl[(nt * 16 + li) * 136 + ko];
      acc[nt] = __builtin_amdgcn_mfma_f32_16x16x32_bf16(a, b, acc[nt], 0, 0, 0);
    }
  }
#pragma unroll
  for (int nt = 0; nt < 8; ++nt) {
    int col = nt * 16 + li;
#pragma unroll
    for (int r = 0; r < 4; ++r) {
      int gi = row0 + m0 + quad * 4 + r;
      if (gi < n) {
        float v = acc[nt][r] + bias[nt];
        if (col < 64) out[(size_t)gi * 64 + col] = v;              // mu
        else          out[(size_t)(n + gi) * 64 + (col - 64)] = v; // logvar
      }
    }
  }
}

extern "C" void kernel_launch(void* const* d_in, const int* in_sizes, int n_in,
                              void* d_out, int out_size, void* d_ws, size_t ws_size,
                              hipStream_t stream) {
  const float* x   = (const float*)d_in[0];
  const int*   ei  = (const int*)d_in[1];   // [2, E], row0 = src, row1 = dst
  const float* W1  = (const float*)d_in[3];
  const float* b1  = (const float*)d_in[4];
  const float* Wmu = (const float*)d_in[5];
  const float* bmu = (const float*)d_in[6];
  const float* Wlv = (const float*)d_in[7];
  const float* blv = (const float*)d_in[8];
  float* out = (float*)d_out;

  const int n = in_sizes[0] / 128;
  const int E = in_sizes[1] / 2;

  // workspace layout (float units)
  float* ws = (float*)d_ws;
  size_t p = 0;
  int* cnt    = (int*)(ws + p); p += n;
  int* ocount = (int*)(ws + p); p += 1;
  p = (p + 3) & ~(size_t)3;  // 16B align
  int* ell    = (int*)(ws + p); p += (size_t)n * ELLK;
  int2* ovf   = (int2*)(ws + p); p += (size_t)OCAP * 2;
  unsigned* A = (unsigned*)(ws + p); p += (size_t)n * 64;  // n*128 bf16
  unsigned* H = (unsigned*)(ws + p); p += (size_t)n * 64;
  unsigned* G = (unsigned*)(ws + p); p += (size_t)n * 64;
  unsigned short* Wt1 = (unsigned short*)(ws + p); p += 8192;  // 128x128 bf16
  unsigned short* Wt2 = (unsigned short*)(ws + p); p += 8192;

  int nbz = (n + 255) / 256;
  int eb  = (E + 255) / 256;
  int gblk = (n + 63) / 64;

  // 1) zero cnt/ocount + weight transpose
  k_setup<<<nbz + 128, 256, 0, stream>>>(W1, Wmu, Wlv, Wt1, Wt2, cnt, ocount, n, nbz);
  // 2) fused: A = bf16(x @ W1)  ||  ELL build (atomics hide under GEMM)
  k_gemm1_fill<<<gblk + eb, 256, 0, stream>>>(x, Wt1, (unsigned short*)A, ei,
                                              cnt, ell, ovf, ocount, n, E, gblk);
  int sblk = (n + 3) / 4;  // one wave per node
  // 3) layer 1: H = bf16(relu(agg(A) + b1))
  k_spmm<true><<<sblk, 256, 0, stream>>>(cnt, ell, ovf, ocount, A, H,
                                         (const float2*)b1, n);
  // 4) layer 2: G = bf16(agg(H))
  k_spmm<false><<<sblk, 256, 0, stream>>>(cnt, ell, ovf, ocount, H, G, nullptr, n);
  // 5) out = [G@Wmu+bmu | G@Wlv+blv]
  k_gemm2_mfma<<<gblk, 256, 0, stream>>>((const unsigned short*)G, Wt2, bmu, blv, out, n);
}